// Round 6
// baseline (1915.318 us; speedup 1.0000x reference)
//
#include <hip/hip_runtime.h>
#include <math.h>

#define N_NODES 50000
#define N_EDGES 400000
#define N_GRAPHS 512
#define TBL 2048
#define EPSBN 1e-5f

__device__ __forceinline__ float softplusf(float x) {
  return fmaxf(x, 0.0f) + log1pf(expf(-fabsf(x)));
}
__device__ __forceinline__ float sigmoidf(float x) {
  return 1.0f / (1.0f + expf(-x));
}
__device__ __forceinline__ void fma4(float4& acc, float s, const float4& w) {
  acc.x = fmaf(s, w.x, acc.x);
  acc.y = fmaf(s, w.y, acc.y);
  acc.z = fmaf(s, w.z, acc.z);
  acc.w = fmaf(s, w.w, acc.w);
}

// ---------------- CSR build (graph static across layers: build once) -------
__global__ void k_hist(const int* __restrict__ dst, int* __restrict__ deg) {
  const int e = blockIdx.x * blockDim.x + threadIdx.x;
  if (e < N_EDGES) atomicAdd(&deg[dst[e]], 1);
}

// Trivially-correct two-phase strip scan, single 1024-thread block.
__global__ void k_scan(const int* __restrict__ deg, int* __restrict__ rowptr,
                       int* __restrict__ cursor) {
  __shared__ int ssum[1024];
  const int t = threadIdx.x;
  const int strip = (N_NODES + 1023) / 1024;  // 49
  const int a = t * strip;
  const int b = min(N_NODES, a + strip);
  int s = 0;
  for (int i = a; i < b; ++i) s += deg[i];
  ssum[t] = s;
  __syncthreads();
  if (t == 0) {
    int run = 0;
    for (int i = 0; i < 1024; ++i) {
      const int x = ssum[i];
      ssum[i] = run;
      run += x;
    }
    rowptr[N_NODES] = run;
  }
  __syncthreads();
  int run = ssum[t];
  for (int i = a; i < b; ++i) {
    rowptr[i] = run;
    cursor[i] = run;
    run += deg[i];
  }
}

// Per edge: slot in CSR; pre-extract src node and clamped RBF-table coord.
__global__ void k_scatter(const int* __restrict__ src, const int* __restrict__ dst,
                          const float* __restrict__ bond,
                          int* __restrict__ cursor,
                          int* __restrict__ csr_src, float* __restrict__ csr_f) {
  const int e = blockIdx.x * blockDim.x + threadIdx.x;
  if (e >= N_EDGES) return;
  const int d2 = dst[e];
  const int pos = atomicAdd(&cursor[d2], 1);
  csr_src[pos] = src[e];
  float f = bond[e] * ((float)(TBL - 1) / 8.0f);
  csr_f[pos] = fminf(fmaxf(f, 0.0f), (float)(TBL - 1));
}

// ---------------- h = atom @ W_emb + b_emb   [N,92]@[92,64] ----------------
__global__ void k_emb(const float* __restrict__ atom,
                      const float* __restrict__ Wemb,
                      const float* __restrict__ bemb,
                      float* __restrict__ h) {
  __shared__ float sW[92 * 64];
  __shared__ float sA[32 * 92];
  const int tid = threadIdx.x;
  for (int i = tid; i < 92 * 64; i += 256) sW[i] = Wemb[i];
  const int t0 = blockIdx.x * 32;
  const int nt = min(32, N_NODES - t0);
  {
    const float* srcp = atom + (size_t)t0 * 92;
    const int tot = nt * 92;
    for (int i = tid; i < tot; i += 256) sA[i] = srcp[i];
  }
  __syncthreads();
  const int col = tid & 63;
  const int ng = tid >> 6;
  const float bb = bemb[col];
  float acc[8];
#pragma unroll
  for (int i = 0; i < 8; ++i) acc[i] = bb;
  for (int kc = 0; kc < 92; kc += 4) {
    const float w0 = sW[(kc + 0) * 64 + col];
    const float w1 = sW[(kc + 1) * 64 + col];
    const float w2 = sW[(kc + 2) * 64 + col];
    const float w3 = sW[(kc + 3) * 64 + col];
#pragma unroll
    for (int i = 0; i < 8; ++i) {
      const float4 a = *(const float4*)&sA[(ng * 8 + i) * 92 + kc];
      acc[i] = fmaf(a.x, w0, acc[i]);
      acc[i] = fmaf(a.y, w1, acc[i]);
      acc[i] = fmaf(a.z, w2, acc[i]);
      acc[i] = fmaf(a.w, w3, acc[i]);
    }
  }
#pragma unroll
  for (int i = 0; i < 8; ++i) {
    const int n = t0 + ng * 8 + i;
    if (n < N_NODES) h[(size_t)n * 64 + col] = acc[i];
  }
}

// ---------------- PA/PB = h @ [Wi|Wu] split by src/dst halves --------------
__global__ void k_pq(const float* __restrict__ h,
                     const float* __restrict__ Wi_l,
                     const float* __restrict__ Wu_l,
                     float* __restrict__ PA,
                     float* __restrict__ PB) {
  __shared__ float sWA[64 * 128];
  __shared__ float sWB[64 * 128];
  __shared__ float sH[32 * 64];
  const int tid = threadIdx.x;

  for (int i = tid; i < 64 * 64; i += 256) {
    const int k = i >> 6, c = i & 63;
    sWA[k * 128 + c]      = Wi_l[k * 64 + c];
    sWA[k * 128 + 64 + c] = Wu_l[k * 64 + c];
    sWB[k * 128 + c]      = Wi_l[(64 + k) * 64 + c];
    sWB[k * 128 + 64 + c] = Wu_l[(64 + k) * 64 + c];
  }
  const int t0 = blockIdx.x * 32;
  const int nt = min(32, N_NODES - t0);
  {
    const float4* srcp = (const float4*)(h + (size_t)t0 * 64);
    const int tot4 = nt * 16;
    float4* dstp = (float4*)sH;
    for (int i = tid; i < tot4; i += 256) dstp[i] = srcp[i];
  }
  __syncthreads();

  const int wave = tid >> 6, lane = tid & 63;
  const float* wcol = (lane < 32) ? (sWA + 4 * lane) : (sWB + 4 * (lane - 32));
  const int jj = (lane < 32) ? 4 * lane : 4 * (lane - 32);
  float* OUTb = (lane < 32) ? PA : PB;

  float4 acc[8];
#pragma unroll
  for (int i = 0; i < 8; ++i) acc[i] = make_float4(0.f, 0.f, 0.f, 0.f);
  for (int kc = 0; kc < 64; kc += 4) {
    const float4 w0 = *(const float4*)(wcol + (kc + 0) * 128);
    const float4 w1 = *(const float4*)(wcol + (kc + 1) * 128);
    const float4 w2 = *(const float4*)(wcol + (kc + 2) * 128);
    const float4 w3 = *(const float4*)(wcol + (kc + 3) * 128);
#pragma unroll
    for (int i = 0; i < 8; ++i) {
      const float4 a = *(const float4*)&sH[(wave * 8 + i) * 64 + kc];
      fma4(acc[i], a.x, w0);
      fma4(acc[i], a.y, w1);
      fma4(acc[i], a.z, w2);
      fma4(acc[i], a.w, w3);
    }
  }
#pragma unroll
  for (int i = 0; i < 8; ++i) {
    const int n = t0 + wave * 8 + i;
    if (n < N_NODES) *(float4*)&OUTb[(size_t)n * 128 + jj] = acc[i];
  }
}

// -------- tbl[t][128] = [ sum_k rbf(d_t,k)*Wi[128+k][:] | same for Wu ] ----
__global__ void k_tbl(const float* __restrict__ Wi_l,
                      const float* __restrict__ Wu_l,
                      float* __restrict__ tbl) {
  const int wave = threadIdx.x >> 6, lane = threadIdx.x & 63;
  const int t = blockIdx.x * (blockDim.x >> 6) + wave;
  if (t >= TBL) return;
  const float d = 8.0f * (float)t / (float)(TBL - 1);
  float gi_ = 0.f, gu_ = 0.f;
#pragma unroll
  for (int k = 0; k < 32; ++k) {
    const float c = 8.0f * (float)k / 31.0f;
    const float dd = d - c;
    const float r = expf(-3.875f * dd * dd);
    gi_ = fmaf(r, Wi_l[(128 + k) * 64 + lane], gi_);
    gu_ = fmaf(r, Wu_l[(128 + k) * 64 + lane], gu_);
  }
  tbl[(size_t)t * 128 + lane] = gi_;
  tbl[(size_t)t * 128 + 64 + lane] = gu_;
}

// ---- Pass 1 (node-centric over CSR): column sums/sumsq of gate/upd pre ----
__global__ void k_edge_stats(const int* __restrict__ rowptr,
                             const int* __restrict__ csr_src,
                             const float* __restrict__ csr_f,
                             const float* __restrict__ PA,
                             const float* __restrict__ PB,
                             const float* __restrict__ tbl,
                             float* __restrict__ stats) {
  const int wave = threadIdx.x >> 6, lane = threadIdx.x & 63;
  const int wid = blockIdx.x * (blockDim.x >> 6) + wave;
  const int nw = gridDim.x * (blockDim.x >> 6);
  const float* PAj = PA + lane;
  const float* tbj = tbl + lane;
  float sg = 0.f, qg = 0.f, su = 0.f, qu = 0.f;
  for (int n = wid; n < N_NODES; n += nw) {
    const int r0 = rowptr[n], r1 = rowptr[n + 1];
    if (r0 == r1) continue;
    const float pbg = PB[(size_t)n * 128 + lane];
    const float pbu = PB[(size_t)n * 128 + 64 + lane];
    for (int k = r0; k < r1; ++k) {
      const int s = csr_src[k];
      const float cf = csr_f[k];
      const int i0 = min((int)cf, TBL - 2);
      const float fr = cf - (float)i0;
      const float* ta = tbj + (size_t)i0 * 128;
      const float pag = PAj[(size_t)s * 128];
      const float pau = PAj[(size_t)s * 128 + 64];
      const float yg = pag + pbg + fmaf(fr, ta[128] - ta[0], ta[0]);
      const float yu = pau + pbu + fmaf(fr, ta[192] - ta[64], ta[64]);
      sg += yg; qg = fmaf(yg, yg, qg);
      su += yu; qu = fmaf(yu, yu, qu);
    }
  }
  __shared__ float red[4][4][64];
  red[0][wave][lane] = sg;
  red[1][wave][lane] = qg;
  red[2][wave][lane] = su;
  red[3][wave][lane] = qu;
  __syncthreads();
  const float v = red[wave][0][lane] + red[wave][1][lane] +
                  red[wave][2][lane] + red[wave][3][lane];
  atomicAdd(&stats[wave * 64 + lane], v);
}

// BN scale/shift for gate & upd (R3-proven separate kernel).
__global__ void k_fin_gu(const float* __restrict__ stats,
                         const float* __restrict__ gi_l, const float* __restrict__ bti_l,
                         const float* __restrict__ gu_l, const float* __restrict__ btu_l,
                         float* __restrict__ coefs) {
  const int j = threadIdx.x;
  const float invE = 1.0f / (float)N_EDGES;
  float m = stats[j] * invE;
  float v = fmaxf(stats[64 + j] * invE - m * m, 0.0f);
  float a = gi_l[j] * rsqrtf(v + EPSBN);
  coefs[j] = a;
  coefs[64 + j] = fmaf(-m, a, bti_l[j]);
  m = stats[128 + j] * invE;
  v = fmaxf(stats[192 + j] * invE - m * m, 0.0f);
  a = gu_l[j] * rsqrtf(v + EPSBN);
  coefs[128 + j] = a;
  coefs[192 + j] = fmaf(-m, a, btu_l[j]);
}

// ---- Pass 2: per-node message sum (no atomics) + fused agg-stats ----------
// msum written into PBm[n][0:64] after that row's Q values are consumed
// (same thread reads then writes its own row -> race-free).
__global__ void k_edge_apply(const int* __restrict__ rowptr,
                             const int* __restrict__ csr_src,
                             const float* __restrict__ csr_f,
                             const float* __restrict__ PA,
                             float* PBm,
                             const float* __restrict__ tbl,
                             const float* __restrict__ coefs,
                             float* __restrict__ stats) {
  const int wave = threadIdx.x >> 6, lane = threadIdx.x & 63;
  const int wid = blockIdx.x * (blockDim.x >> 6) + wave;
  const int nw = gridDim.x * (blockDim.x >> 6);
  const float ag = coefs[lane], bg = coefs[64 + lane];
  const float au = coefs[128 + lane], bu = coefs[192 + lane];
  const float* PAj = PA + lane;
  const float* tbj = tbl + lane;
  float ssum = 0.f, sqsum = 0.f;
  for (int n = wid; n < N_NODES; n += nw) {
    const int r0 = rowptr[n], r1 = rowptr[n + 1];
    float msum = 0.f;
    if (r0 < r1) {
      const float pbg = PBm[(size_t)n * 128 + lane];
      const float pbu = PBm[(size_t)n * 128 + 64 + lane];
      for (int k = r0; k < r1; ++k) {
        const int s = csr_src[k];
        const float cf = csr_f[k];
        const int i0 = min((int)cf, TBL - 2);
        const float fr = cf - (float)i0;
        const float* ta = tbj + (size_t)i0 * 128;
        const float pag = PAj[(size_t)s * 128];
        const float pau = PAj[(size_t)s * 128 + 64];
        const float yg = pag + pbg + fmaf(fr, ta[128] - ta[0], ta[0]);
        const float yu = pau + pbu + fmaf(fr, ta[192] - ta[64], ta[64]);
        msum += sigmoidf(fmaf(ag, yg, bg)) * softplusf(fmaf(au, yu, bu));
      }
    }
    PBm[(size_t)n * 128 + lane] = msum;
    ssum += msum;
    sqsum = fmaf(msum, msum, sqsum);
  }
  __shared__ float red[2][4][64];
  red[0][wave][lane] = ssum;
  red[1][wave][lane] = sqsum;
  __syncthreads();
  if (wave < 2) {
    const float vv = red[wave][0][lane] + red[wave][1][lane] +
                     red[wave][2][lane] + red[wave][3][lane];
    atomicAdd(&stats[256 + wave * 64 + lane], vv);
  }
}

// BN coefs for the aggregate (R3-proven separate kernel).
__global__ void k_fin_agg(const float* __restrict__ stats,
                          const float* __restrict__ gbn_l, const float* __restrict__ bbn_l,
                          float* __restrict__ coefs) {
  const int j = threadIdx.x;
  const float invN = 1.0f / (float)N_NODES;
  const float m = stats[256 + j] * invN;
  const float v = fmaxf(stats[320 + j] * invN - m * m, 0.0f);
  const float a = gbn_l[j] * rsqrtf(v + EPSBN);
  coefs[256 + j] = a;
  coefs[320 + j] = fmaf(-m, a, bbn_l[j]);
}

// h = softplus(h + BN(agg)); agg lives in PBm[n][0:64] (stride 128).
__global__ void k_hupd(float* __restrict__ h, const float* __restrict__ PBm,
                       const float* __restrict__ coefs) {
  const int stride = blockDim.x * gridDim.x;
  for (int i = blockIdx.x * blockDim.x + threadIdx.x; i < N_NODES * 64; i += stride) {
    const int j = i & 63;
    const int n = i >> 6;
    const float x = h[i] + fmaf(coefs[256 + j], PBm[(size_t)n * 128 + j], coefs[320 + j]);
    h[i] = softplusf(x);
  }
}

// R3-proven atomic pooling.
__global__ void k_pool(const float* __restrict__ h, const int* __restrict__ gid,
                       float* __restrict__ pooled, float* __restrict__ counts) {
  const int wave = threadIdx.x >> 6, lane = threadIdx.x & 63;
  const int wpb = blockDim.x >> 6;
  const int nw = wpb * gridDim.x;
  for (int n = blockIdx.x * wpb + wave; n < N_NODES; n += nw) {
    const int g = gid[n];
    atomicAdd(&pooled[(size_t)g * 64 + lane], h[(size_t)n * 64 + lane]);
    if (lane == 0) atomicAdd(&counts[g], 1.0f);
  }
}

__global__ void k_final(const float* __restrict__ pooled, const float* __restrict__ counts,
                        const float* __restrict__ Wfc, const float* __restrict__ bfc,
                        const float* __restrict__ Wout, const float* __restrict__ bout,
                        float* __restrict__ out) {
  __shared__ float f1[64];
  __shared__ float red[128];
  const int g = blockIdx.x, t = threadIdx.x;
  if (t < 64) {
    const float c = fmaxf(counts[g], 1.0f);
    f1[t] = softplusf(pooled[(size_t)g * 64 + t] / c);
  }
  __syncthreads();
  float acc = bfc[t];
#pragma unroll
  for (int k = 0; k < 64; ++k) acc = fmaf(f1[k], Wfc[k * 128 + t], acc);
  red[t] = softplusf(softplusf(acc)) * Wout[t];
  __syncthreads();
  for (int s2 = 64; s2 > 0; s2 >>= 1) {
    if (t < s2) red[t] += red[t + s2];
    __syncthreads();
  }
  if (t == 0) out[g] = red[0] + bout[0];
}

extern "C" void kernel_launch(void* const* d_in, const int* in_sizes, int n_in,
                              void* d_out, int out_size, void* d_ws, size_t ws_size,
                              hipStream_t stream) {
  const float* atom = (const float*)d_in[0];
  const float* bond = (const float*)d_in[1];
  const int* src = (const int*)d_in[2];
  const int* dst = (const int*)d_in[3];
  const int* gid = (const int*)d_in[4];
  const float* Wemb = (const float*)d_in[5];
  const float* bemb = (const float*)d_in[6];
  const float* Wi = (const float*)d_in[7];
  // d_in[8] = bi  — cancels under BN (mean-shift), unused
  const float* gi = (const float*)d_in[9];
  const float* bti = (const float*)d_in[10];
  const float* Wu = (const float*)d_in[11];
  // d_in[12] = bu — cancels under BN, unused
  const float* gub = (const float*)d_in[13];
  const float* btu = (const float*)d_in[14];
  const float* gbn = (const float*)d_in[15];
  const float* bbn = (const float*)d_in[16];
  const float* Wfc = (const float*)d_in[17];
  const float* bfc = (const float*)d_in[18];
  const float* Wout = (const float*)d_in[19];
  const float* bout = (const float*)d_in[20];

  // workspace layout (4B units), total ~66 MB
  float* h = (float*)d_ws;                               // N*64
  float* PA = h + (size_t)N_NODES * 64;                  // N*128
  float* PB = PA + (size_t)N_NODES * 128;                // N*128 (Q + msum)
  float* tbl = PB + (size_t)N_NODES * 128;               // TBL*128
  float* stats = tbl + (size_t)TBL * 128;                // 384
  float* coefs = stats + 384;                            // 384
  // zero-region (single memset): deg | pooled | counts
  int* deg = (int*)(coefs + 384);                        // N
  float* pooled = (float*)(deg + N_NODES);               // G*64
  float* counts = pooled + (size_t)N_GRAPHS * 64;        // G
  int* rowptr = (int*)(counts + N_GRAPHS);               // N+1
  int* cursor = rowptr + N_NODES + 1;                    // N
  int* csr_src = cursor + N_NODES;                       // E
  float* csr_f = (float*)(csr_src + N_EDGES);            // E

  const int ntiles = (N_NODES + 31) / 32;   // 1563
  const int egrid = (N_EDGES + 255) / 256;  // 1563

  // ---- CSR build (once; graph constant across layers) ----
  (void)hipMemsetAsync(deg, 0,
                       (size_t)(N_NODES + N_GRAPHS * 64 + N_GRAPHS) * 4, stream);
  k_hist<<<egrid, 256, 0, stream>>>(dst, deg);
  k_scan<<<1, 1024, 0, stream>>>(deg, rowptr, cursor);
  k_scatter<<<egrid, 256, 0, stream>>>(src, dst, bond, cursor, csr_src, csr_f);

  k_emb<<<ntiles, 256, 0, stream>>>(atom, Wemb, bemb, h);
  for (int l = 0; l < 3; ++l) {
    const float* Wi_l = Wi + (size_t)l * 160 * 64;
    const float* Wu_l = Wu + (size_t)l * 160 * 64;
    (void)hipMemsetAsync(stats, 0, 384 * sizeof(float), stream);
    k_pq<<<ntiles, 256, 0, stream>>>(h, Wi_l, Wu_l, PA, PB);
    k_tbl<<<TBL / 4, 256, 0, stream>>>(Wi_l, Wu_l, tbl);
    k_edge_stats<<<1024, 256, 0, stream>>>(rowptr, csr_src, csr_f,
                                           PA, PB, tbl, stats);
    k_fin_gu<<<1, 64, 0, stream>>>(stats, gi + l * 64, bti + l * 64,
                                   gub + l * 64, btu + l * 64, coefs);
    k_edge_apply<<<1024, 256, 0, stream>>>(rowptr, csr_src, csr_f,
                                           PA, PB, tbl, coefs, stats);
    k_fin_agg<<<1, 64, 0, stream>>>(stats, gbn + l * 64, bbn + l * 64, coefs);
    k_hupd<<<1024, 256, 0, stream>>>(h, PB, coefs);
  }
  k_pool<<<512, 256, 0, stream>>>(h, gid, pooled, counts);
  k_final<<<N_GRAPHS, 128, 0, stream>>>(pooled, counts, Wfc, bfc, Wout, bout,
                                        (float*)d_out);
}

// Round 7
// 1867.755 us; speedup vs baseline: 1.0255x; 1.0255x over previous
//
#include <hip/hip_runtime.h>
#include <hip/hip_fp16.h>
#include <math.h>

#define N_NODES 50000
#define N_EDGES 400000
#define N_GRAPHS 512
#define TBL 512
#define EPSBN 1e-5f

__device__ __forceinline__ float softplusf(float x) {
  return fmaxf(x, 0.0f) + log1pf(expf(-fabsf(x)));
}
__device__ __forceinline__ float sigmoidf(float x) {
  return 1.0f / (1.0f + expf(-x));
}
__device__ __forceinline__ void fma4(float4& acc, float s, const float4& w) {
  acc.x = fmaf(s, w.x, acc.x);
  acc.y = fmaf(s, w.y, acc.y);
  acc.z = fmaf(s, w.z, acc.z);
  acc.w = fmaf(s, w.w, acc.w);
}

// ---------------- CSR build (graph static across layers: build once) -------
__global__ void k_hist(const int* __restrict__ dst, int* __restrict__ deg) {
  const int e = blockIdx.x * blockDim.x + threadIdx.x;
  if (e < N_EDGES) atomicAdd(&deg[dst[e]], 1);
}

// Two-phase strip scan, single 1024-thread block (R6-proven).
__global__ void k_scan(const int* __restrict__ deg, int* __restrict__ rowptr,
                       int* __restrict__ cursor) {
  __shared__ int ssum[1024];
  const int t = threadIdx.x;
  const int strip = (N_NODES + 1023) / 1024;  // 49
  const int a = t * strip;
  const int b = min(N_NODES, a + strip);
  int s = 0;
  for (int i = a; i < b; ++i) s += deg[i];
  ssum[t] = s;
  __syncthreads();
  if (t == 0) {
    int run = 0;
    for (int i = 0; i < 1024; ++i) {
      const int x = ssum[i];
      ssum[i] = run;
      run += x;
    }
    rowptr[N_NODES] = run;
  }
  __syncthreads();
  int run = ssum[t];
  for (int i = a; i < b; ++i) {
    rowptr[i] = run;
    cursor[i] = run;
    run += deg[i];
  }
}

// Per edge: slot in CSR; pre-extract src node and clamped RBF-table coord.
__global__ void k_scatter(const int* __restrict__ src, const int* __restrict__ dst,
                          const float* __restrict__ bond,
                          int* __restrict__ cursor,
                          int* __restrict__ csr_src, float* __restrict__ csr_f) {
  const int e = blockIdx.x * blockDim.x + threadIdx.x;
  if (e >= N_EDGES) return;
  const int d2 = dst[e];
  const int pos = atomicAdd(&cursor[d2], 1);
  csr_src[pos] = src[e];
  float f = bond[e] * ((float)(TBL - 1) / 8.0f);
  csr_f[pos] = fminf(fmaxf(f, 0.0f), (float)(TBL - 1));
}

// ---------------- h = atom @ W_emb + b_emb   [N,92]@[92,64] ----------------
__global__ void k_emb(const float* __restrict__ atom,
                      const float* __restrict__ Wemb,
                      const float* __restrict__ bemb,
                      float* __restrict__ h) {
  __shared__ float sW[92 * 64];
  __shared__ float sA[32 * 92];
  const int tid = threadIdx.x;
  for (int i = tid; i < 92 * 64; i += 256) sW[i] = Wemb[i];
  const int t0 = blockIdx.x * 32;
  const int nt = min(32, N_NODES - t0);
  {
    const float* srcp = atom + (size_t)t0 * 92;
    const int tot = nt * 92;
    for (int i = tid; i < tot; i += 256) sA[i] = srcp[i];
  }
  __syncthreads();
  const int col = tid & 63;
  const int ng = tid >> 6;
  const float bb = bemb[col];
  float acc[8];
#pragma unroll
  for (int i = 0; i < 8; ++i) acc[i] = bb;
  for (int kc = 0; kc < 92; kc += 4) {
    const float w0 = sW[(kc + 0) * 64 + col];
    const float w1 = sW[(kc + 1) * 64 + col];
    const float w2 = sW[(kc + 2) * 64 + col];
    const float w3 = sW[(kc + 3) * 64 + col];
#pragma unroll
    for (int i = 0; i < 8; ++i) {
      const float4 a = *(const float4*)&sA[(ng * 8 + i) * 92 + kc];
      acc[i] = fmaf(a.x, w0, acc[i]);
      acc[i] = fmaf(a.y, w1, acc[i]);
      acc[i] = fmaf(a.z, w2, acc[i]);
      acc[i] = fmaf(a.w, w3, acc[i]);
    }
  }
#pragma unroll
  for (int i = 0; i < 8; ++i) {
    const int n = t0 + ng * 8 + i;
    if (n < N_NODES) h[(size_t)n * 64 + col] = acc[i];
  }
}

// ---------------- PA/PB = h @ [Wi|Wu] split by src/dst halves, fp16 out ----
__global__ void k_pq(const float* __restrict__ h,
                     const float* __restrict__ Wi_l,
                     const float* __restrict__ Wu_l,
                     __half* __restrict__ PA,
                     __half* __restrict__ PB) {
  __shared__ float sWA[64 * 128];
  __shared__ float sWB[64 * 128];
  __shared__ float sH[32 * 64];
  const int tid = threadIdx.x;

  for (int i = tid; i < 64 * 64; i += 256) {
    const int k = i >> 6, c = i & 63;
    sWA[k * 128 + c]      = Wi_l[k * 64 + c];
    sWA[k * 128 + 64 + c] = Wu_l[k * 64 + c];
    sWB[k * 128 + c]      = Wi_l[(64 + k) * 64 + c];
    sWB[k * 128 + 64 + c] = Wu_l[(64 + k) * 64 + c];
  }
  const int t0 = blockIdx.x * 32;
  const int nt = min(32, N_NODES - t0);
  {
    const float4* srcp = (const float4*)(h + (size_t)t0 * 64);
    const int tot4 = nt * 16;
    float4* dstp = (float4*)sH;
    for (int i = tid; i < tot4; i += 256) dstp[i] = srcp[i];
  }
  __syncthreads();

  const int wave = tid >> 6, lane = tid & 63;
  const float* wcol = (lane < 32) ? (sWA + 4 * lane) : (sWB + 4 * (lane - 32));
  const int jj = (lane < 32) ? 4 * lane : 4 * (lane - 32);
  __half* OUTb = (lane < 32) ? PA : PB;

  float4 acc[8];
#pragma unroll
  for (int i = 0; i < 8; ++i) acc[i] = make_float4(0.f, 0.f, 0.f, 0.f);
  for (int kc = 0; kc < 64; kc += 4) {
    const float4 w0 = *(const float4*)(wcol + (kc + 0) * 128);
    const float4 w1 = *(const float4*)(wcol + (kc + 1) * 128);
    const float4 w2 = *(const float4*)(wcol + (kc + 2) * 128);
    const float4 w3 = *(const float4*)(wcol + (kc + 3) * 128);
#pragma unroll
    for (int i = 0; i < 8; ++i) {
      const float4 a = *(const float4*)&sH[(wave * 8 + i) * 64 + kc];
      fma4(acc[i], a.x, w0);
      fma4(acc[i], a.y, w1);
      fma4(acc[i], a.z, w2);
      fma4(acc[i], a.w, w3);
    }
  }
#pragma unroll
  for (int i = 0; i < 8; ++i) {
    const int n = t0 + wave * 8 + i;
    if (n < N_NODES) {
      ushort4 u;
      u.x = __half_as_ushort(__float2half_rn(acc[i].x));
      u.y = __half_as_ushort(__float2half_rn(acc[i].y));
      u.z = __half_as_ushort(__float2half_rn(acc[i].z));
      u.w = __half_as_ushort(__float2half_rn(acc[i].w));
      *(ushort4*)&OUTb[(size_t)n * 128 + jj] = u;
    }
  }
}

// -------- tbl[t][128] = [ sum_k rbf(d_t,k)*Wi[128+k][:] | same for Wu ] ----
__global__ void k_tbl(const float* __restrict__ Wi_l,
                      const float* __restrict__ Wu_l,
                      __half* __restrict__ tbl) {
  const int wave = threadIdx.x >> 6, lane = threadIdx.x & 63;
  const int t = blockIdx.x * (blockDim.x >> 6) + wave;
  if (t >= TBL) return;
  const float d = 8.0f * (float)t / (float)(TBL - 1);
  float gi_ = 0.f, gu_ = 0.f;
#pragma unroll
  for (int k = 0; k < 32; ++k) {
    const float c = 8.0f * (float)k / 31.0f;
    const float dd = d - c;
    const float r = expf(-3.875f * dd * dd);
    gi_ = fmaf(r, Wi_l[(128 + k) * 64 + lane], gi_);
    gu_ = fmaf(r, Wu_l[(128 + k) * 64 + lane], gu_);
  }
  tbl[(size_t)t * 128 + lane] = __float2half_rn(gi_);
  tbl[(size_t)t * 128 + 64 + lane] = __float2half_rn(gu_);
}

// ---- Pass 1 (node-centric over CSR): column sums/sumsq of gate/upd pre ----
__global__ void k_edge_stats(const int* __restrict__ rowptr,
                             const int* __restrict__ csr_src,
                             const float* __restrict__ csr_f,
                             const __half* __restrict__ PA,
                             const __half* __restrict__ PB,
                             const __half* __restrict__ tbl,
                             float* __restrict__ stats) {
  const int wave = threadIdx.x >> 6, lane = threadIdx.x & 63;
  const int wid = blockIdx.x * (blockDim.x >> 6) + wave;
  const int nw = gridDim.x * (blockDim.x >> 6);
  const __half* PAj = PA + lane;
  const __half* tbj = tbl + lane;
  float sg = 0.f, qg = 0.f, su = 0.f, qu = 0.f;
  for (int n = wid; n < N_NODES; n += nw) {
    const int r0 = rowptr[n], r1 = rowptr[n + 1];
    if (r0 == r1) continue;
    const float pbg = __half2float(PB[(size_t)n * 128 + lane]);
    const float pbu = __half2float(PB[(size_t)n * 128 + 64 + lane]);
    for (int k = r0; k < r1; ++k) {
      const int s = csr_src[k];
      const float cf = csr_f[k];
      const int i0 = min((int)cf, TBL - 2);
      const float fr = cf - (float)i0;
      const __half* ta = tbj + (size_t)i0 * 128;
      const float pag = __half2float(PAj[(size_t)s * 128]);
      const float pau = __half2float(PAj[(size_t)s * 128 + 64]);
      const float tg0 = __half2float(ta[0]), tg1 = __half2float(ta[128]);
      const float tu0 = __half2float(ta[64]), tu1 = __half2float(ta[192]);
      const float yg = pag + pbg + fmaf(fr, tg1 - tg0, tg0);
      const float yu = pau + pbu + fmaf(fr, tu1 - tu0, tu0);
      sg += yg; qg = fmaf(yg, yg, qg);
      su += yu; qu = fmaf(yu, yu, qu);
    }
  }
  __shared__ float red[4][4][64];
  red[0][wave][lane] = sg;
  red[1][wave][lane] = qg;
  red[2][wave][lane] = su;
  red[3][wave][lane] = qu;
  __syncthreads();
  const float v = red[wave][0][lane] + red[wave][1][lane] +
                  red[wave][2][lane] + red[wave][3][lane];
  atomicAdd(&stats[wave * 64 + lane], v);
}

// BN scale/shift for gate & upd.
__global__ void k_fin_gu(const float* __restrict__ stats,
                         const float* __restrict__ gi_l, const float* __restrict__ bti_l,
                         const float* __restrict__ gu_l, const float* __restrict__ btu_l,
                         float* __restrict__ coefs) {
  const int j = threadIdx.x;
  const float invE = 1.0f / (float)N_EDGES;
  float m = stats[j] * invE;
  float v = fmaxf(stats[64 + j] * invE - m * m, 0.0f);
  float a = gi_l[j] * rsqrtf(v + EPSBN);
  coefs[j] = a;
  coefs[64 + j] = fmaf(-m, a, bti_l[j]);
  m = stats[128 + j] * invE;
  v = fmaxf(stats[192 + j] * invE - m * m, 0.0f);
  a = gu_l[j] * rsqrtf(v + EPSBN);
  coefs[128 + j] = a;
  coefs[192 + j] = fmaf(-m, a, btu_l[j]);
}

// ---- Pass 2: per-node message sum (no atomics) + fused agg-stats ----------
__global__ void k_edge_apply(const int* __restrict__ rowptr,
                             const int* __restrict__ csr_src,
                             const float* __restrict__ csr_f,
                             const __half* __restrict__ PA,
                             const __half* __restrict__ PB,
                             const __half* __restrict__ tbl,
                             const float* __restrict__ coefs,
                             float* __restrict__ agg,
                             float* __restrict__ stats) {
  const int wave = threadIdx.x >> 6, lane = threadIdx.x & 63;
  const int wid = blockIdx.x * (blockDim.x >> 6) + wave;
  const int nw = gridDim.x * (blockDim.x >> 6);
  const float ag = coefs[lane], bg = coefs[64 + lane];
  const float au = coefs[128 + lane], bu = coefs[192 + lane];
  const __half* PAj = PA + lane;
  const __half* tbj = tbl + lane;
  float ssum = 0.f, sqsum = 0.f;
  for (int n = wid; n < N_NODES; n += nw) {
    const int r0 = rowptr[n], r1 = rowptr[n + 1];
    float msum = 0.f;
    if (r0 < r1) {
      const float pbg = __half2float(PB[(size_t)n * 128 + lane]);
      const float pbu = __half2float(PB[(size_t)n * 128 + 64 + lane]);
      for (int k = r0; k < r1; ++k) {
        const int s = csr_src[k];
        const float cf = csr_f[k];
        const int i0 = min((int)cf, TBL - 2);
        const float fr = cf - (float)i0;
        const __half* ta = tbj + (size_t)i0 * 128;
        const float pag = __half2float(PAj[(size_t)s * 128]);
        const float pau = __half2float(PAj[(size_t)s * 128 + 64]);
        const float tg0 = __half2float(ta[0]), tg1 = __half2float(ta[128]);
        const float tu0 = __half2float(ta[64]), tu1 = __half2float(ta[192]);
        const float yg = pag + pbg + fmaf(fr, tg1 - tg0, tg0);
        const float yu = pau + pbu + fmaf(fr, tu1 - tu0, tu0);
        msum += sigmoidf(fmaf(ag, yg, bg)) * softplusf(fmaf(au, yu, bu));
      }
    }
    agg[(size_t)n * 64 + lane] = msum;
    ssum += msum;
    sqsum = fmaf(msum, msum, sqsum);
  }
  __shared__ float red[2][4][64];
  red[0][wave][lane] = ssum;
  red[1][wave][lane] = sqsum;
  __syncthreads();
  if (wave < 2) {
    const float vv = red[wave][0][lane] + red[wave][1][lane] +
                     red[wave][2][lane] + red[wave][3][lane];
    atomicAdd(&stats[256 + wave * 64 + lane], vv);
  }
}

// BN coefs for the aggregate.
__global__ void k_fin_agg(const float* __restrict__ stats,
                          const float* __restrict__ gbn_l, const float* __restrict__ bbn_l,
                          float* __restrict__ coefs) {
  const int j = threadIdx.x;
  const float invN = 1.0f / (float)N_NODES;
  const float m = stats[256 + j] * invN;
  const float v = fmaxf(stats[320 + j] * invN - m * m, 0.0f);
  const float a = gbn_l[j] * rsqrtf(v + EPSBN);
  coefs[256 + j] = a;
  coefs[320 + j] = fmaf(-m, a, bbn_l[j]);
}

// h = softplus(h + BN(agg))
__global__ void k_hupd(float* __restrict__ h, const float* __restrict__ agg,
                       const float* __restrict__ coefs) {
  const int stride = blockDim.x * gridDim.x;
  for (int i = blockIdx.x * blockDim.x + threadIdx.x; i < N_NODES * 64; i += stride) {
    const int j = i & 63;
    const float x = h[i] + fmaf(coefs[256 + j], agg[i], coefs[320 + j]);
    h[i] = softplusf(x);
  }
}

__global__ void k_pool(const float* __restrict__ h, const int* __restrict__ gid,
                       float* __restrict__ pooled, float* __restrict__ counts) {
  const int wave = threadIdx.x >> 6, lane = threadIdx.x & 63;
  const int wpb = blockDim.x >> 6;
  const int nw = wpb * gridDim.x;
  for (int n = blockIdx.x * wpb + wave; n < N_NODES; n += nw) {
    const int g = gid[n];
    atomicAdd(&pooled[(size_t)g * 64 + lane], h[(size_t)n * 64 + lane]);
    if (lane == 0) atomicAdd(&counts[g], 1.0f);
  }
}

__global__ void k_final(const float* __restrict__ pooled, const float* __restrict__ counts,
                        const float* __restrict__ Wfc, const float* __restrict__ bfc,
                        const float* __restrict__ Wout, const float* __restrict__ bout,
                        float* __restrict__ out) {
  __shared__ float f1[64];
  __shared__ float red[128];
  const int g = blockIdx.x, t = threadIdx.x;
  if (t < 64) {
    const float c = fmaxf(counts[g], 1.0f);
    f1[t] = softplusf(pooled[(size_t)g * 64 + t] / c);
  }
  __syncthreads();
  float acc = bfc[t];
#pragma unroll
  for (int k = 0; k < 64; ++k) acc = fmaf(f1[k], Wfc[k * 128 + t], acc);
  red[t] = softplusf(softplusf(acc)) * Wout[t];
  __syncthreads();
  for (int s2 = 64; s2 > 0; s2 >>= 1) {
    if (t < s2) red[t] += red[t + s2];
    __syncthreads();
  }
  if (t == 0) out[g] = red[0] + bout[0];
}

extern "C" void kernel_launch(void* const* d_in, const int* in_sizes, int n_in,
                              void* d_out, int out_size, void* d_ws, size_t ws_size,
                              hipStream_t stream) {
  const float* atom = (const float*)d_in[0];
  const float* bond = (const float*)d_in[1];
  const int* src = (const int*)d_in[2];
  const int* dst = (const int*)d_in[3];
  const int* gid = (const int*)d_in[4];
  const float* Wemb = (const float*)d_in[5];
  const float* bemb = (const float*)d_in[6];
  const float* Wi = (const float*)d_in[7];
  // d_in[8] = bi  — cancels under BN (mean-shift), unused
  const float* gi = (const float*)d_in[9];
  const float* bti = (const float*)d_in[10];
  const float* Wu = (const float*)d_in[11];
  // d_in[12] = bu — cancels under BN, unused
  const float* gub = (const float*)d_in[13];
  const float* btu = (const float*)d_in[14];
  const float* gbn = (const float*)d_in[15];
  const float* bbn = (const float*)d_in[16];
  const float* Wfc = (const float*)d_in[17];
  const float* bfc = (const float*)d_in[18];
  const float* Wout = (const float*)d_in[19];
  const float* bout = (const float*)d_in[20];

  // workspace layout (4B units), total ~55 MB
  float* h = (float*)d_ws;                               // N*64 f32
  float* agg = h + (size_t)N_NODES * 64;                 // N*64 f32
  __half* PA = (__half*)(agg + (size_t)N_NODES * 64);    // N*128 f16
  __half* PB = PA + (size_t)N_NODES * 128;               // N*128 f16
  __half* tbl = PB + (size_t)N_NODES * 128;              // TBL*128 f16
  float* stats = (float*)(tbl + (size_t)TBL * 128);      // 384
  float* coefs = stats + 384;                            // 384
  // zero-region (single memset): deg | pooled | counts
  int* deg = (int*)(coefs + 384);                        // N
  float* pooled = (float*)(deg + N_NODES);               // G*64
  float* counts = pooled + (size_t)N_GRAPHS * 64;        // G
  int* rowptr = (int*)(counts + N_GRAPHS);               // N+1
  int* cursor = rowptr + N_NODES + 1;                    // N
  int* csr_src = cursor + N_NODES;                       // E
  float* csr_f = (float*)(csr_src + N_EDGES);            // E

  const int ntiles = (N_NODES + 31) / 32;   // 1563
  const int egrid = (N_EDGES + 255) / 256;  // 1563

  // ---- CSR build (once; graph constant across layers) ----
  (void)hipMemsetAsync(deg, 0,
                       (size_t)(N_NODES + N_GRAPHS * 64 + N_GRAPHS) * 4, stream);
  k_hist<<<egrid, 256, 0, stream>>>(dst, deg);
  k_scan<<<1, 1024, 0, stream>>>(deg, rowptr, cursor);
  k_scatter<<<egrid, 256, 0, stream>>>(src, dst, bond, cursor, csr_src, csr_f);

  k_emb<<<ntiles, 256, 0, stream>>>(atom, Wemb, bemb, h);
  for (int l = 0; l < 3; ++l) {
    const float* Wi_l = Wi + (size_t)l * 160 * 64;
    const float* Wu_l = Wu + (size_t)l * 160 * 64;
    (void)hipMemsetAsync(stats, 0, 384 * sizeof(float), stream);
    k_pq<<<ntiles, 256, 0, stream>>>(h, Wi_l, Wu_l, PA, PB);
    k_tbl<<<TBL / 4, 256, 0, stream>>>(Wi_l, Wu_l, tbl);
    k_edge_stats<<<2048, 256, 0, stream>>>(rowptr, csr_src, csr_f,
                                           PA, PB, tbl, stats);
    k_fin_gu<<<1, 64, 0, stream>>>(stats, gi + l * 64, bti + l * 64,
                                   gub + l * 64, btu + l * 64, coefs);
    k_edge_apply<<<2048, 256, 0, stream>>>(rowptr, csr_src, csr_f,
                                           PA, PB, tbl, coefs, agg, stats);
    k_fin_agg<<<1, 64, 0, stream>>>(stats, gbn + l * 64, bbn + l * 64, coefs);
    k_hupd<<<1024, 256, 0, stream>>>(h, agg, coefs);
  }
  k_pool<<<512, 256, 0, stream>>>(h, gid, pooled, counts);
  k_final<<<N_GRAPHS, 128, 0, stream>>>(pooled, counts, Wfc, bfc, Wout, bout,
                                        (float*)d_out);
}